// Round 1
// baseline (294.298 us; speedup 1.0000x reference)
//
#include <hip/hip_runtime.h>
#include <hip/hip_bf16.h>

// Problem constants
// x2d: (16, 64, 128, 128) f32   -> replication pad (1,2,1,2) -> 131x131
// conv 3x3 VALID, 64->256 ch    -> proj_map (16, 256, 129, 129)
// x3d: (16, 8, 16, 64, 64) f32  -> zeropad3d(1), max depth, mean ch -> (16,1,66,66)
// bilinear resize half-pixel    -> g (16,1,129,129)
// out = mean_{h,w} clip(proj*g, 0, 6)  -> (16, 256)

typedef __bf16 bf16x8_t __attribute__((ext_vector_type(8)));
typedef float  f32x4    __attribute__((ext_vector_type(4)));

#define ROWB     16768          // 131 cols * 64 ch * 2B, bytes per padded row (ch-last)
#define XPT_IMG  (131 * ROWB)   // 2,196,608 B per batch image
#define TILE_B   (3 * ROWB)     // 50,304 B staged per block (3 rows)

// ---------------------------------------------------------------------------
// K0: zero the output accumulator (d_out is poisoned 0xAA before every launch)
__global__ void k_zero(float* __restrict__ out) {
    int t = blockIdx.x * 256 + threadIdx.x;
    if (t < 16 * 256) out[t] = 0.0f;
}

// ---------------------------------------------------------------------------
// K1: x2d (b,c,h,w) f32 -> xpT (b, r(131), col(131), ch(64)) bf16,
// replication-padded, XOR-swizzled within each 128B channel block:
//   byte within row = col*128 + ((ch*2) ^ ((col&7)<<4))
__global__ void k_transpose(const float* __restrict__ x2d, char* __restrict__ xpT) {
    int t = blockIdx.x * 256 + threadIdx.x;
    if (t >= 16 * 131 * 131) return;
    int col = t % 131;
    int r   = (t / 131) % 131;
    int b   = t / (131 * 131);
    int h = min(max(r   - 1, 0), 127);
    int w = min(max(col - 1, 0), 127);
    const float* src = x2d + ((size_t)b * 64 * 128 + h) * 128 + w; // + c*16384
    char* dst = xpT + (size_t)b * XPT_IMG + r * ROWB + col * 128;
    int sw = (col & 7) << 4;
    #pragma unroll
    for (int c8 = 0; c8 < 8; ++c8) {
        bf16x8_t v;
        #pragma unroll
        for (int e = 0; e < 8; ++e) {
            v[e] = (__bf16)src[(size_t)(c8 * 8 + e) * 16384];
        }
        *(bf16x8_t*)(dst + ((c8 * 16) ^ sw)) = v;
    }
}

// ---------------------------------------------------------------------------
// K2: W_proj (256, 576) f32, torch k-order (c*9 + tap) -> B-fragment layout:
// Bfrag[kk][nf][lane] = 8 bf16, k = kk*32 + (lane>>4)*8 + e, n = nf*16 + (lane&15)
// with our K order k = tap*64 + c  (kk = tap*2 + kc, c = kc*32 + (lane>>4)*8 + e)
__global__ void k_bfrag(const float* __restrict__ Wp, char* __restrict__ Bfrag) {
    int t = blockIdx.x * 256 + threadIdx.x;
    if (t >= 18 * 16 * 64) return;
    int lane = t & 63;
    int nf   = (t >> 6) & 15;
    int kk   = t >> 10;
    int tap  = kk >> 1;
    int cb   = (kk & 1) * 32 + ((lane >> 4) << 3);
    int n    = nf * 16 + (lane & 15);
    bf16x8_t v;
    #pragma unroll
    for (int e = 0; e < 8; ++e)
        v[e] = (__bf16)Wp[n * 576 + (cb + e) * 9 + tap];
    *(bf16x8_t*)(Bfrag + (size_t)t * 16) = v;
}

// ---------------------------------------------------------------------------
// K3: gating 66x66: border = 0 (zero pad), interior = mean_c max(0, max_d x3d)
__global__ void k_gating(const float* __restrict__ x3d, float* __restrict__ g66) {
    int t = blockIdx.x * 256 + threadIdx.x;
    if (t >= 16 * 66 * 66) return;
    int x = t % 66;
    int y = (t / 66) % 66;
    int b = t / (66 * 66);
    float outv = 0.0f;
    if (x > 0 && x < 65 && y > 0 && y < 65) {
        float s = 0.0f;
        #pragma unroll
        for (int c = 0; c < 8; ++c) {
            float m = 0.0f;  // zero depth-pad planes participate in max
            #pragma unroll
            for (int d = 0; d < 16; ++d) {
                float v = x3d[(size_t)((b * 8 + c) * 16 + d) * 4096 + (y - 1) * 64 + (x - 1)];
                m = fmaxf(m, v);
            }
            s += m;
        }
        outv = s * 0.125f;
    }
    g66[t] = outv;
}

// ---------------------------------------------------------------------------
// K4: bilinear resize 66x66 -> 129x129, half-pixel centers, edge clamp
__global__ void k_resize(const float* __restrict__ g66, float* __restrict__ g129) {
    int t = blockIdx.x * 256 + threadIdx.x;
    if (t >= 16 * 129 * 129) return;
    int j = t % 129;
    int i = (t / 129) % 129;
    int b = t / (129 * 129);
    const float sc = 66.0f / 129.0f;
    float sy = (i + 0.5f) * sc - 0.5f;
    float sx = (j + 0.5f) * sc - 0.5f;
    float y0f = floorf(sy), x0f = floorf(sx);
    float fy = sy - y0f, fx = sx - x0f;
    int y0 = (int)y0f, x0 = (int)x0f;
    int y0c = min(max(y0, 0), 65), y1c = min(max(y0 + 1, 0), 65);
    int x0c = min(max(x0, 0), 65), x1c = min(max(x0 + 1, 0), 65);
    const float* g = g66 + b * 66 * 66;
    float v = (1.0f - fy) * ((1.0f - fx) * g[y0c * 66 + x0c] + fx * g[y0c * 66 + x1c])
            +         fy  * ((1.0f - fx) * g[y1c * 66 + x0c] + fx * g[y1c * 66 + x1c]);
    g129[t] = v;
}

// ---------------------------------------------------------------------------
// K5: main fused conv + gate + relu6 + global average pool.
// One block per (batch, output row y). M = 129 (padded to 144 = 9x16 frags),
// N = 256 (16 frags, 4 per wave), K = 576 (9 taps x 2 chunks of 32).
__global__ __launch_bounds__(256) void k_conv(
    const char* __restrict__ xpT, const char* __restrict__ Bfrag,
    const float* __restrict__ g129, const float* __restrict__ bias,
    float* __restrict__ out)
{
    __shared__ uint4 smem4[TILE_B / 16];
    __shared__ float gld[132];
    char* smem = (char*)smem4;

    const int y    = blockIdx.x;
    const int b    = blockIdx.y;
    const int tid  = threadIdx.x;
    const int lane = tid & 63;
    const int w    = tid >> 6;

    // ---- stage A tile (3 padded rows, bf16 ch-last, pre-swizzled) via global_load_lds
    const char* gsrc = xpT + (size_t)b * XPT_IMG + (size_t)y * ROWB;
    for (int j = w; j < 50; j += 4) {           // 50304 = 49*1024 + 128
        int woff = j * 1024;
        if (woff + lane * 16 < TILE_B) {
            __builtin_amdgcn_global_load_lds(
                (const __attribute__((address_space(1))) void*)(gsrc + woff + lane * 16),
                (__attribute__((address_space(3))) void*)(smem + woff),
                16, 0, 0);
        }
    }
    if (tid < 129) gld[tid] = g129[(b * 129 + y) * 129 + tid];
    __syncthreads();   // drains vmcnt (global_load_lds) + lgkm

    f32x4 acc[9][4];
    #pragma unroll
    for (int mf = 0; mf < 9; ++mf)
        #pragma unroll
        for (int nf = 0; nf < 4; ++nf)
            acc[mf][nf] = (f32x4){0.f, 0.f, 0.f, 0.f};

    const int l15  = lane & 15;
    const int lhi  = lane >> 4;

    for (int tap = 0; tap < 9; ++tap) {
        const int ki  = tap / 3;
        const int kj  = tap - ki * 3;
        const int kib = ki * ROWB;
        #pragma unroll
        for (int kc = 0; kc < 2; ++kc) {
            const int kk = tap * 2 + kc;
            bf16x8_t bfr[4];
            #pragma unroll
            for (int nf = 0; nf < 4; ++nf)
                bfr[nf] = *(const bf16x8_t*)(Bfrag +
                    ((size_t)(kk * 16 + (w * 4 + nf)) * 64 + lane) * 16);
            const int chb = kc * 64 + (lhi << 4);   // channel byte offset within 128B block
            #pragma unroll
            for (int mf = 0; mf < 9; ++mf) {
                int col = mf * 16 + l15 + kj;
                col = min(col, 130);                 // guard (only pad-tail frags hit this)
                int off = kib + col * 128 + (chb ^ ((col & 7) << 4));
                bf16x8_t a = *(const bf16x8_t*)(smem + off);
                #pragma unroll
                for (int nf = 0; nf < 4; ++nf)
                    acc[mf][nf] = __builtin_amdgcn_mfma_f32_16x16x32_bf16(
                        a, bfr[nf], acc[mf][nf], 0, 0, 0);
            }
        }
    }

    // ---- epilogue: bias, gate, relu6, spatial sum, atomic accumulate
    float bval[4];
    #pragma unroll
    for (int nf = 0; nf < 4; ++nf)
        bval[nf] = bias[w * 64 + nf * 16 + l15];

    float s[4] = {0.f, 0.f, 0.f, 0.f};
    #pragma unroll
    for (int mf = 0; mf < 9; ++mf) {
        #pragma unroll
        for (int r = 0; r < 4; ++r) {
            int x = mf * 16 + (lhi << 2) + r;      // D row m = (lane>>4)*4 + r
            if (x < 129) {
                float gv = gld[x];
                #pragma unroll
                for (int nf = 0; nf < 4; ++nf) {
                    float v = (acc[mf][nf][r] + bval[nf]) * gv;
                    v = fminf(fmaxf(v, 0.0f), 6.0f);
                    s[nf] += v;
                }
            }
        }
    }
    #pragma unroll
    for (int nf = 0; nf < 4; ++nf) {
        s[nf] += __shfl_xor(s[nf], 16);
        s[nf] += __shfl_xor(s[nf], 32);
    }
    if (lane < 16) {
        #pragma unroll
        for (int nf = 0; nf < 4; ++nf)
            atomicAdd(&out[b * 256 + w * 64 + nf * 16 + lane],
                      s[nf] * (1.0f / 16641.0f));
    }
}

// ---------------------------------------------------------------------------
extern "C" void kernel_launch(void* const* d_in, const int* in_sizes, int n_in,
                              void* d_out, int out_size, void* d_ws, size_t ws_size,
                              hipStream_t stream) {
    (void)in_sizes; (void)n_in; (void)out_size; (void)ws_size;
    const float* x2d = (const float*)d_in[0];
    const float* x3d = (const float*)d_in[1];
    const float* Wp  = (const float*)d_in[2];
    const float* bp  = (const float*)d_in[3];
    float* out = (float*)d_out;
    char*  ws  = (char*)d_ws;

    // workspace layout (all 16B aligned)
    char*  xpT   = ws;                                    // 16*131*16768 = 35,137,536 B
    char*  Bfrag = ws + (size_t)16 * XPT_IMG;             // 294,912 B
    float* g66   = (float*)(Bfrag + 294912);              // 278,784 B
    float* g129  = (float*)((char*)g66 + 278784);         // 1,065,024 B

    k_zero     <<<16,   256, 0, stream>>>(out);
    k_transpose<<<(16 * 131 * 131 + 255) / 256, 256, 0, stream>>>(x2d, xpT);
    k_bfrag    <<<72,   256, 0, stream>>>(Wp, Bfrag);
    k_gating   <<<(16 * 66 * 66 + 255) / 256, 256, 0, stream>>>(x3d, g66);
    k_resize   <<<(16 * 129 * 129 + 255) / 256, 256, 0, stream>>>(g66, g129);

    dim3 grid(129, 16);
    k_conv<<<grid, 256, 0, stream>>>(xpT, Bfrag, g129, bp, out);
}